// Round 2
// baseline (291.463 us; speedup 1.0000x reference)
//
#include <hip/hip_runtime.h>

typedef unsigned short u16;
typedef __bf16 bf16x8 __attribute__((ext_vector_type(8)));
typedef float f32x4 __attribute__((ext_vector_type(4)));

#define DEV __device__ __forceinline__

constexpr int D       = 128;
constexpr int NB      = 2048;     // batch rows
constexpr int C_REAL  = 100000;   // memory rows
constexpr int BN      = 128;      // cols per chunk
constexpr int NSPLIT  = 32;       // column splits
constexpr int CHUNKS  = 25;       // chunks per split
constexpr int CPAD    = NSPLIT * CHUNKS * BN; // 102400 padded cols
constexpr int BM      = 256;      // rows per block in k_dist

// workspace layout (all 256B aligned); total ~28.4 MB
constexpr size_t OFF_MEMB = 0;                                  // CPAD*128 u16
constexpr size_t OFF_MEMN = (size_t)CPAD * D * 2;               // CPAD f32
constexpr size_t OFF_ENCB = OFF_MEMN + (size_t)CPAD * 4;        // NB*128 u16
constexpr size_t OFF_ENCN = OFF_ENCB + (size_t)NB * D * 2;      // NB f32
constexpr size_t OFF_PART = OFF_ENCN + (size_t)NB * 4;          // NB*NSPLIT*10 f32

DEV u16 f2bf(float x) {
    unsigned u = __float_as_uint(x);
    u += 0x7FFFu + ((u >> 16) & 1u);   // RNE to bf16
    return (u16)(u >> 16);
}
DEV float bf2f(u16 b) { return __uint_as_float(((unsigned)b) << 16); }

// branchless insert of v into ascending 10-list (keeps 10 smallest)
DEV void ins10(float (&L)[10], float v) {
    L[9] = __builtin_amdgcn_fmed3f(L[8], L[9], v);
    L[8] = __builtin_amdgcn_fmed3f(L[7], L[8], v);
    L[7] = __builtin_amdgcn_fmed3f(L[6], L[7], v);
    L[6] = __builtin_amdgcn_fmed3f(L[5], L[6], v);
    L[5] = __builtin_amdgcn_fmed3f(L[4], L[5], v);
    L[4] = __builtin_amdgcn_fmed3f(L[3], L[4], v);
    L[3] = __builtin_amdgcn_fmed3f(L[2], L[2] < v ? L[3] : L[3], v); // placeholder avoided below
    // (see full unrolled version below)
}

// NOTE: the placeholder above is not used; real implementation:
DEV void ins10f(float (&L)[10], float v) {
    L[9] = __builtin_amdgcn_fmed3f(L[8], L[9], v);
    L[8] = __builtin_amdgcn_fmed3f(L[7], L[8], v);
    L[7] = __builtin_amdgcn_fmed3f(L[6], L[7], v);
    L[6] = __builtin_amdgcn_fmed3f(L[5], L[6], v);
    L[5] = __builtin_amdgcn_fmed3f(L[4], L[5], v);
    L[4] = __builtin_amdgcn_fmed3f(L[3], L[4], v);
    L[3] = __builtin_amdgcn_fmed3f(L[2], L[3], v);
    L[2] = __builtin_amdgcn_fmed3f(L[1], L[2], v);
    L[1] = __builtin_amdgcn_fmed3f(L[0], L[1], v);
    L[0] = fminf(L[0], v);
}

// ---------------- kernel 1: encoder ----------------
__global__ __launch_bounds__(128)
void k_encoder(const float* __restrict__ state, const float* __restrict__ W1,
               const float* __restrict__ b1, const float* __restrict__ W2,
               const float* __restrict__ b2, u16* __restrict__ encB,
               float* __restrict__ encN)
{
    __shared__ __align__(16) float sA[8][128];
    __shared__ __align__(16) float sH[8][128];
    const int tid = threadIdx.x;
    const int rbase = blockIdx.x * 8;

#pragma unroll
    for (int r = 0; r < 8; ++r)
        sA[r][tid] = state[(size_t)(rbase + r) * D + tid];
    __syncthreads();

    float acc[8];
#pragma unroll
    for (int r = 0; r < 8; ++r) acc[r] = b1[tid];
    for (int d4 = 0; d4 < 32; ++d4) {
        float w0 = W1[(d4 * 4 + 0) * D + tid];
        float w1 = W1[(d4 * 4 + 1) * D + tid];
        float w2 = W1[(d4 * 4 + 2) * D + tid];
        float w3 = W1[(d4 * 4 + 3) * D + tid];
#pragma unroll
        for (int r = 0; r < 8; ++r) {
            float4 sv = *reinterpret_cast<const float4*>(&sA[r][d4 * 4]);
            acc[r] = fmaf(sv.w, w3, fmaf(sv.z, w2, fmaf(sv.y, w1, fmaf(sv.x, w0, acc[r]))));
        }
    }
#pragma unroll
    for (int r = 0; r < 8; ++r) sH[r][tid] = fmaxf(acc[r], 0.f);
    __syncthreads();

#pragma unroll
    for (int r = 0; r < 8; ++r) acc[r] = b2[tid];
    for (int d4 = 0; d4 < 32; ++d4) {
        float w0 = W2[(d4 * 4 + 0) * D + tid];
        float w1 = W2[(d4 * 4 + 1) * D + tid];
        float w2 = W2[(d4 * 4 + 2) * D + tid];
        float w3 = W2[(d4 * 4 + 3) * D + tid];
#pragma unroll
        for (int r = 0; r < 8; ++r) {
            float4 sv = *reinterpret_cast<const float4*>(&sH[r][d4 * 4]);
            acc[r] = fmaf(sv.w, w3, fmaf(sv.z, w2, fmaf(sv.y, w1, fmaf(sv.x, w0, acc[r]))));
        }
    }

#pragma unroll
    for (int r = 0; r < 8; ++r) {
        u16 bb = f2bf(acc[r]);
        encB[(size_t)(rbase + r) * D + tid] = bb;
        float vv = bf2f(bb);
        sA[r][tid] = vv * vv;   // safe: layer-1 reads of sA ended before prior barrier
    }
    __syncthreads();
    if (tid < 8) {
        float s = 0.f;
        for (int d = 0; d < 128; ++d) s += sA[tid][d];
        encN[rbase + tid] = s;
    }
}

// ---------------- kernel 2: memory -> bf16 + norms (+pad) ----------------
__global__ __launch_bounds__(256)
void k_memprep(const float* __restrict__ mem, u16* __restrict__ memB,
               float* __restrict__ memN)
{
    int g = blockIdx.x * 256 + threadIdx.x;
    int row = g >> 5;
    int l32 = g & 31;
    if (row >= CPAD) return;
    float4 v = make_float4(0.f, 0.f, 0.f, 0.f);
    bool real = row < C_REAL;
    if (real)
        v = *reinterpret_cast<const float4*>(mem + (size_t)row * D + l32 * 4);
    u16 c0 = f2bf(v.x), c1 = f2bf(v.y), c2 = f2bf(v.z), c3 = f2bf(v.w);
    float r0 = bf2f(c0), r1 = bf2f(c1), r2 = bf2f(c2), r3 = bf2f(c3);
    uint2 pk;
    pk.x = (unsigned)c0 | ((unsigned)c1 << 16);
    pk.y = (unsigned)c2 | ((unsigned)c3 << 16);
    *reinterpret_cast<uint2*>(memB + (size_t)row * D + l32 * 4) = pk;
    float s = r0 * r0 + r1 * r1 + r2 * r2 + r3 * r3;
    s += __shfl_xor(s, 16);
    s += __shfl_xor(s, 8);
    s += __shfl_xor(s, 4);
    s += __shfl_xor(s, 2);
    s += __shfl_xor(s, 1);
    if (l32 == 0) memN[row] = real ? s : __builtin_inff();
}

// ---------------- kernel 3: fused distance GEMM + per-split top-10 ----------------
// key tracked per candidate = memN - 2*dot (encN added in k_final; same ordering)
__global__ __launch_bounds__(512, 2)
void k_dist(const u16* __restrict__ encB,
            const u16* __restrict__ memB, const float* __restrict__ memN,
            float* __restrict__ partials)
{
    __shared__ __align__(16) unsigned char btile[32768];  // 128 cols x 128 k bf16, swizzled

    const int tid = threadIdx.x;
    const int w   = tid >> 6;        // wave 0..7
    const int l   = tid & 63;
    const int l15 = l & 15;
    const int lg  = l >> 4;          // 0..3
    const int split = blockIdx.x;    // 0..31
    const int rbase = blockIdx.y * BM;
    const long cbase0 = (long)split * (CHUNKS * BN);

    // A fragments in registers: rows rbase + w*32 + rf*16 + l15, all of K=128
    bf16x8 afrag[2][4];
#pragma unroll
    for (int rf = 0; rf < 2; ++rf) {
        const u16* ap = encB + (size_t)(rbase + w * 32 + rf * 16 + l15) * D;
#pragma unroll
        for (int ks = 0; ks < 4; ++ks)
            afrag[rf][ks] = *reinterpret_cast<const bf16x8*>(ap + ks * 32 + lg * 8);
    }

    float lst[8][10];
#pragma unroll
    for (int i = 0; i < 8; ++i)
#pragma unroll
        for (int t = 0; t < 10; ++t) lst[i][t] = __builtin_inff();

    // hoisted swizzled LDS addresses.
    // write: thread covers 64B of col (tid>>2); p = (tid*64 + u*16) ^ ((col&7)<<4)
    const int wbase = (tid << 6) ^ (((tid >> 2) & 7) << 4);
    // read: col = cgroup*16 + l15 (cgroup mult of 8 -> swizzle = (l15&7)<<4)
    // p = cgroup*4096 + [ (l15<<8)|(ks<<6)|(lg<<4) ] ^ ((l15&7)<<4)
    const int rbase_ln = ((l15 << 8) | (lg << 4)) ^ ((l15 & 7) << 4);
    const unsigned char* rdp[4];
#pragma unroll
    for (int ks = 0; ks < 4; ++ks) rdp[ks] = btile + (rbase_ln ^ (ks << 6));

    // prefetch chunk 0 into registers
    uint4 stg[4];
    {
        const unsigned char* src = (const unsigned char*)(memB + cbase0 * D);
#pragma unroll
        for (int u = 0; u < 4; ++u)
            stg[u] = *reinterpret_cast<const uint4*>(src + tid * 64 + u * 16);
    }

#pragma unroll 1
    for (int ch = 0; ch < CHUNKS; ++ch) {
        // write staged regs to LDS (swizzled)
#pragma unroll
        for (int u = 0; u < 4; ++u)
            *reinterpret_cast<uint4*>(btile + (wbase ^ (u << 4))) = stg[u];
        __syncthreads();
        // prefetch next chunk (clamped; latency hides under MFMA/epilogue)
        {
            int chn = (ch + 1 < CHUNKS) ? ch + 1 : ch;
            const unsigned char* src =
                (const unsigned char*)(memB + (cbase0 + (long)chn * BN) * D);
#pragma unroll
            for (int u = 0; u < 4; ++u)
                stg[u] = *reinterpret_cast<const uint4*>(src + tid * 64 + u * 16);
        }
        const long cbase = cbase0 + (long)ch * BN;

#pragma unroll
        for (int h = 0; h < 2; ++h) {   // two 64-col halves to bound acc VGPRs
            float mn[4];
#pragma unroll
            for (int c4 = 0; c4 < 4; ++c4)
                mn[c4] = memN[cbase + (h * 4 + c4) * 16 + l15];
            f32x4 acc[2][4] = {};
#pragma unroll
            for (int c4 = 0; c4 < 4; ++c4) {
                const int cg = h * 4 + c4;      // col group (mult-of-16 base / 16)
#pragma unroll
                for (int ks = 0; ks < 4; ++ks) {
                    bf16x8 bfr = *reinterpret_cast<const bf16x8*>(rdp[ks] + (cg << 12));
                    acc[0][c4] = __builtin_amdgcn_mfma_f32_16x16x32_bf16(
                        afrag[0][ks], bfr, acc[0][c4], 0, 0, 0);
                    acc[1][c4] = __builtin_amdgcn_mfma_f32_16x16x32_bf16(
                        afrag[1][ks], bfr, acc[1][c4], 0, 0, 0);
                }
            }
            // epilogue: key = memN - 2*dot, branchless med3 top-10
#pragma unroll
            for (int c4 = 0; c4 < 4; ++c4)
#pragma unroll
                for (int rf = 0; rf < 2; ++rf)
#pragma unroll
                    for (int j = 0; j < 4; ++j) {
                        float key = fmaf(-2.0f, acc[rf][c4][j], mn[c4]);
                        ins10f(lst[rf * 4 + j], key);
                    }
        }
        __syncthreads();
    }

    // exact in-register merge across the 16 col-lanes of each row:
    // 4-level xor tree; both partners insert each other's sorted 10 -> identical union top-10
#pragma unroll
    for (int li = 0; li < 8; ++li) {
#pragma unroll
        for (int d = 1; d <= 8; d <<= 1) {
            float t[10];
#pragma unroll
            for (int q = 0; q < 10; ++q) t[q] = __shfl_xor(lst[li][q], d);
#pragma unroll
            for (int q = 0; q < 10; ++q) ins10f(lst[li], t[q]);
        }
        if (l15 == 0) {
            int row = rbase + w * 32 + (li >> 2) * 16 + lg * 4 + (li & 3);
            float* dst = partials + (size_t)row * (NSPLIT * 10) + split * 10;
#pragma unroll
            for (int q = 0; q < 10; ++q) dst[q] = lst[li][q];
        }
    }
}

// ---------------- kernel 4: final merge + mean of sqrt (1 wave / row) ----------------
__global__ __launch_bounds__(256)
void k_final(const float* __restrict__ partials, const float* __restrict__ encN,
             float* __restrict__ out)
{
    const int w = threadIdx.x >> 6;
    const int l = threadIdx.x & 63;
    const int row = blockIdx.x * 4 + w;

    float L[10];
#pragma unroll
    for (int t = 0; t < 10; ++t) L[t] = __builtin_inff();
    const float* p = partials + (size_t)row * (NSPLIT * 10) + l * 5;
#pragma unroll
    for (int t = 0; t < 5; ++t) ins10f(L, p[t]);
#pragma unroll
    for (int d = 1; d <= 32; d <<= 1) {
        float t[10];
#pragma unroll
        for (int q = 0; q < 10; ++q) t[q] = __shfl_xor(L[q], d);
#pragma unroll
        for (int q = 0; q < 10; ++q) ins10f(L, t[q]);
    }
    if (l == 0) {
        float en = encN[row];
        float s = 0.f;
#pragma unroll
        for (int t = 0; t < 10; ++t)
            s += sqrtf(fmaxf(en + L[t], 1e-12f));
        out[row] = s * 0.1f;
    }
}

extern "C" void kernel_launch(void* const* d_in, const int* in_sizes, int n_in,
                              void* d_out, int out_size, void* d_ws, size_t ws_size,
                              hipStream_t stream)
{
    const float* state = (const float*)d_in[0];
    const float* W1    = (const float*)d_in[1];
    const float* b1    = (const float*)d_in[2];
    const float* W2    = (const float*)d_in[3];
    const float* b2    = (const float*)d_in[4];
    const float* mem   = (const float*)d_in[5];
    float* out = (float*)d_out;
    char* ws = (char*)d_ws;
    u16*   memB = (u16*)(ws + OFF_MEMB);
    float* memN = (float*)(ws + OFF_MEMN);
    u16*   encB = (u16*)(ws + OFF_ENCB);
    float* encN = (float*)(ws + OFF_ENCN);
    float* partials = (float*)(ws + OFF_PART);

    hipLaunchKernelGGL(k_encoder, dim3(NB / 8), dim3(128), 0, stream,
                       state, W1, b1, W2, b2, encB, encN);
    hipLaunchKernelGGL(k_memprep, dim3(CPAD * 32 / 256), dim3(256), 0, stream,
                       mem, memB, memN);
    hipLaunchKernelGGL(k_dist, dim3(NSPLIT, NB / BM), dim3(512), 0, stream,
                       encB, memB, memN, partials);
    hipLaunchKernelGGL(k_final, dim3(NB / 4), dim3(256), 0, stream,
                       partials, encN, out);
}

// Round 4
// 235.303 us; speedup vs baseline: 1.2387x; 1.2387x over previous
//
#include <hip/hip_runtime.h>

typedef unsigned short u16;
typedef __bf16 bf16x8 __attribute__((ext_vector_type(8)));
typedef float f32x4 __attribute__((ext_vector_type(4)));

#define DEV __device__ __forceinline__
#define MED3 __builtin_amdgcn_fmed3f
#define MFMA __builtin_amdgcn_mfma_f32_16x16x32_bf16

constexpr int D       = 128;
constexpr int NB      = 2048;     // batch rows
constexpr int C_REAL  = 100000;   // memory rows
constexpr int BN      = 128;      // cols per chunk
constexpr int NSPLIT  = 32;       // column splits
constexpr int CHUNKS  = 25;       // chunks per split
constexpr int CPAD    = NSPLIT * CHUNKS * BN; // 102400 padded cols
constexpr int BM      = 256;      // rows per block in k_dist

// workspace layout (all 256B aligned); total ~28.4 MB
constexpr size_t OFF_MEMB = 0;                                  // CPAD*128 u16
constexpr size_t OFF_MEMN = (size_t)CPAD * D * 2;               // CPAD f32
constexpr size_t OFF_ENCB = OFF_MEMN + (size_t)CPAD * 4;        // NB*128 u16
constexpr size_t OFF_ENCN = OFF_ENCB + (size_t)NB * D * 2;      // NB f32
constexpr size_t OFF_PART = OFF_ENCN + (size_t)NB * 4;          // NB*NSPLIT*10 f32

DEV u16 f2bf(float x) {
    unsigned u = __float_as_uint(x);
    u += 0x7FFFu + ((u >> 16) & 1u);   // RNE to bf16
    return (u16)(u >> 16);
}
DEV float bf2f(u16 b) { return __uint_as_float(((unsigned)b) << 16); }

// ---- top-10 list as named fields: guaranteed register residency ----
struct L10 { float a,b,c,d,e,f,g,h,i,j; };

DEV void linit(L10& L) {
    L.a=L.b=L.c=L.d=L.e=L.f=L.g=L.h=L.i=L.j = __builtin_inff();
}
// branchless insert of x, keeping the 10 smallest (ascending a..j)
DEV void ins(L10& L, float x) {
    L.j = MED3(L.i, L.j, x);
    L.i = MED3(L.h, L.i, x);
    L.h = MED3(L.g, L.h, x);
    L.g = MED3(L.f, L.g, x);
    L.f = MED3(L.e, L.f, x);
    L.e = MED3(L.d, L.e, x);
    L.d = MED3(L.c, L.d, x);
    L.c = MED3(L.b, L.c, x);
    L.b = MED3(L.a, L.b, x);
    L.a = fminf(L.a, x);
}
DEV void mergeX(L10& L, int d) {
    float ta=__shfl_xor(L.a,d), tb=__shfl_xor(L.b,d), tc=__shfl_xor(L.c,d);
    float td=__shfl_xor(L.d,d), te=__shfl_xor(L.e,d), tf=__shfl_xor(L.f,d);
    float tg=__shfl_xor(L.g,d), th=__shfl_xor(L.h,d), ti=__shfl_xor(L.i,d);
    float tj=__shfl_xor(L.j,d);
    ins(L,ta); ins(L,tb); ins(L,tc); ins(L,td); ins(L,te);
    ins(L,tf); ins(L,tg); ins(L,th); ins(L,ti); ins(L,tj);
}
DEV void storeL(const L10& L, float* dst) {
    dst[0]=L.a; dst[1]=L.b; dst[2]=L.c; dst[3]=L.d; dst[4]=L.e;
    dst[5]=L.f; dst[6]=L.g; dst[7]=L.h; dst[8]=L.i; dst[9]=L.j;
}

// ---------------- kernel 1: encoder ----------------
__global__ __launch_bounds__(128)
void k_encoder(const float* __restrict__ state, const float* __restrict__ W1,
               const float* __restrict__ b1, const float* __restrict__ W2,
               const float* __restrict__ b2, u16* __restrict__ encB,
               float* __restrict__ encN)
{
    __shared__ __align__(16) float sA[8][128];
    __shared__ __align__(16) float sH[8][128];
    const int tid = threadIdx.x;
    const int rbase = blockIdx.x * 8;

#pragma unroll
    for (int r = 0; r < 8; ++r)
        sA[r][tid] = state[(size_t)(rbase + r) * D + tid];
    __syncthreads();

    float acc[8];
#pragma unroll
    for (int r = 0; r < 8; ++r) acc[r] = b1[tid];
    for (int d4 = 0; d4 < 32; ++d4) {
        float w0 = W1[(d4 * 4 + 0) * D + tid];
        float w1 = W1[(d4 * 4 + 1) * D + tid];
        float w2 = W1[(d4 * 4 + 2) * D + tid];
        float w3 = W1[(d4 * 4 + 3) * D + tid];
#pragma unroll
        for (int r = 0; r < 8; ++r) {
            float4 sv = *reinterpret_cast<const float4*>(&sA[r][d4 * 4]);
            acc[r] = fmaf(sv.w, w3, fmaf(sv.z, w2, fmaf(sv.y, w1, fmaf(sv.x, w0, acc[r]))));
        }
    }
#pragma unroll
    for (int r = 0; r < 8; ++r) sH[r][tid] = fmaxf(acc[r], 0.f);
    __syncthreads();

#pragma unroll
    for (int r = 0; r < 8; ++r) acc[r] = b2[tid];
    for (int d4 = 0; d4 < 32; ++d4) {
        float w0 = W2[(d4 * 4 + 0) * D + tid];
        float w1 = W2[(d4 * 4 + 1) * D + tid];
        float w2 = W2[(d4 * 4 + 2) * D + tid];
        float w3 = W2[(d4 * 4 + 3) * D + tid];
#pragma unroll
        for (int r = 0; r < 8; ++r) {
            float4 sv = *reinterpret_cast<const float4*>(&sH[r][d4 * 4]);
            acc[r] = fmaf(sv.w, w3, fmaf(sv.z, w2, fmaf(sv.y, w1, fmaf(sv.x, w0, acc[r]))));
        }
    }

#pragma unroll
    for (int r = 0; r < 8; ++r) {
        u16 bb = f2bf(acc[r]);
        encB[(size_t)(rbase + r) * D + tid] = bb;
        float vv = bf2f(bb);
        sA[r][tid] = vv * vv;
    }
    __syncthreads();
    if (tid < 8) {
        float s = 0.f;
        for (int d = 0; d < 128; ++d) s += sA[tid][d];
        encN[rbase + tid] = s;
    }
}

// ---------------- kernel 2: memory -> bf16 + norms (+pad) ----------------
__global__ __launch_bounds__(256)
void k_memprep(const float* __restrict__ mem, u16* __restrict__ memB,
               float* __restrict__ memN)
{
    int g = blockIdx.x * 256 + threadIdx.x;
    int row = g >> 5;
    int l32 = g & 31;
    if (row >= CPAD) return;
    float4 v = make_float4(0.f, 0.f, 0.f, 0.f);
    bool real = row < C_REAL;
    if (real)
        v = *reinterpret_cast<const float4*>(mem + (size_t)row * D + l32 * 4);
    u16 c0 = f2bf(v.x), c1 = f2bf(v.y), c2 = f2bf(v.z), c3 = f2bf(v.w);
    float r0 = bf2f(c0), r1 = bf2f(c1), r2 = bf2f(c2), r3 = bf2f(c3);
    uint2 pk;
    pk.x = (unsigned)c0 | ((unsigned)c1 << 16);
    pk.y = (unsigned)c2 | ((unsigned)c3 << 16);
    *reinterpret_cast<uint2*>(memB + (size_t)row * D + l32 * 4) = pk;
    float s = r0 * r0 + r1 * r1 + r2 * r2 + r3 * r3;
    s += __shfl_xor(s, 16);
    s += __shfl_xor(s, 8);
    s += __shfl_xor(s, 4);
    s += __shfl_xor(s, 2);
    s += __shfl_xor(s, 1);
    if (l32 == 0) memN[row] = real ? s : __builtin_inff();
}

// ---------------- kernel 3: fused distance GEMM + per-split top-10 ----------------
// key per candidate = memN - 2*dot (encN added in k_final; same ordering per row)
__global__ __launch_bounds__(512)
__attribute__((amdgpu_waves_per_eu(2, 2)))
void k_dist(const u16* __restrict__ encB,
            const u16* __restrict__ memB, const float* __restrict__ memN,
            float* __restrict__ partials)
{
    __shared__ __align__(16) unsigned char btile[2][32768]; // double-buffered B chunk

    const int tid = threadIdx.x;
    const int w   = tid >> 6;        // wave 0..7
    const int l   = tid & 63;
    const int l15 = l & 15;
    const int lg  = l >> 4;          // 0..3
    const int split = blockIdx.x;    // 0..31
    const int rbase = blockIdx.y * BM;
    const long cbase0 = (long)split * (CHUNKS * BN);

    // A fragments (K=128) in registers: wave owns rows rbase + w*32 .. +31
    const u16* ap0 = encB + (size_t)(rbase + w * 32 + l15) * D;       // rf=0
    const u16* ap1 = encB + (size_t)(rbase + w * 32 + 16 + l15) * D;  // rf=1
    bf16x8 a00 = *reinterpret_cast<const bf16x8*>(ap0 + 0 * 32 + lg * 8);
    bf16x8 a01 = *reinterpret_cast<const bf16x8*>(ap0 + 1 * 32 + lg * 8);
    bf16x8 a02 = *reinterpret_cast<const bf16x8*>(ap0 + 2 * 32 + lg * 8);
    bf16x8 a03 = *reinterpret_cast<const bf16x8*>(ap0 + 3 * 32 + lg * 8);
    bf16x8 a10 = *reinterpret_cast<const bf16x8*>(ap1 + 0 * 32 + lg * 8);
    bf16x8 a11 = *reinterpret_cast<const bf16x8*>(ap1 + 1 * 32 + lg * 8);
    bf16x8 a12 = *reinterpret_cast<const bf16x8*>(ap1 + 2 * 32 + lg * 8);
    bf16x8 a13 = *reinterpret_cast<const bf16x8*>(ap1 + 3 * 32 + lg * 8);

    L10 T0,T1,T2,T3,T4,T5,T6,T7;
    linit(T0); linit(T1); linit(T2); linit(T3);
    linit(T4); linit(T5); linit(T6); linit(T7);

    // LDS content definition: LDS[x] = chunk[x ^ S(x)], S(x) = ((x>>8)&7)<<4.
    // Writes: lane-contiguous linear (conflict-free); swizzle applied to the
    // GLOBAL source address (intra-256B permutation -> still fully coalesced).
    // write piece u of this thread: p = u*8192 + tid*16
    int wsrcoff[4];
#pragma unroll
    for (int u = 0; u < 4; ++u) {
        int p = (u << 13) | (tid << 4);
        wsrcoff[u] = p ^ (((p >> 8) & 7) << 4);
    }
    // read addresses: q = col*256 + ks*64 + lg*16, col = cg*16 + l15
    // LDS addr = q ^ ((col&7)<<4); per-lane base (cg=0,ks=0..3):
    const int rbl = ((l15 << 8) | (lg << 4)) ^ ((l15 & 7) << 4);
    const int off0 = rbl ^ (0 << 6);
    const int off1 = rbl ^ (1 << 6);
    const int off2 = rbl ^ (2 << 6);
    const int off3 = rbl ^ (3 << 6);

    // prefetch chunk 0 into registers (source pre-swizzled)
    uint4 s0, s1, s2, s3;
    {
        const unsigned char* src = (const unsigned char*)(memB + cbase0 * D);
        s0 = *reinterpret_cast<const uint4*>(src + wsrcoff[0]);
        s1 = *reinterpret_cast<const uint4*>(src + wsrcoff[1]);
        s2 = *reinterpret_cast<const uint4*>(src + wsrcoff[2]);
        s3 = *reinterpret_cast<const uint4*>(src + wsrcoff[3]);
    }

#define KEY8(A0, A1, MN) do { \
    ins(T0, fmaf(-2.0f, (A0)[0], (MN))); \
    ins(T1, fmaf(-2.0f, (A0)[1], (MN))); \
    ins(T2, fmaf(-2.0f, (A0)[2], (MN))); \
    ins(T3, fmaf(-2.0f, (A0)[3], (MN))); \
    ins(T4, fmaf(-2.0f, (A1)[0], (MN))); \
    ins(T5, fmaf(-2.0f, (A1)[1], (MN))); \
    ins(T6, fmaf(-2.0f, (A1)[2], (MN))); \
    ins(T7, fmaf(-2.0f, (A1)[3], (MN))); \
} while (0)

#define DO_CG(CGI, MNV) do { \
    bf16x8 q0 = *reinterpret_cast<const bf16x8*>(bp + (off0 + ((CGI) << 12))); \
    bf16x8 q1 = *reinterpret_cast<const bf16x8*>(bp + (off1 + ((CGI) << 12))); \
    bf16x8 q2 = *reinterpret_cast<const bf16x8*>(bp + (off2 + ((CGI) << 12))); \
    bf16x8 q3 = *reinterpret_cast<const bf16x8*>(bp + (off3 + ((CGI) << 12))); \
    f32x4 ac0 = {0.f, 0.f, 0.f, 0.f}; \
    f32x4 ac1 = {0.f, 0.f, 0.f, 0.f}; \
    ac0 = MFMA(a00, q0, ac0, 0, 0, 0); \
    ac1 = MFMA(a10, q0, ac1, 0, 0, 0); \
    ac0 = MFMA(a01, q1, ac0, 0, 0, 0); \
    ac1 = MFMA(a11, q1, ac1, 0, 0, 0); \
    ac0 = MFMA(a02, q2, ac0, 0, 0, 0); \
    ac1 = MFMA(a12, q2, ac1, 0, 0, 0); \
    ac0 = MFMA(a03, q3, ac0, 0, 0, 0); \
    ac1 = MFMA(a13, q3, ac1, 0, 0, 0); \
    KEY8(ac0, ac1, (MNV)); \
} while (0)

#pragma unroll 1
    for (int ch = 0; ch < CHUNKS; ++ch) {
        // write staged regs to LDS buffer ch&1 (lane-contiguous, conflict-free)
        unsigned char* wb = &btile[ch & 1][0];
        *reinterpret_cast<uint4*>(wb + ((0 << 13) | (tid << 4))) = s0;
        *reinterpret_cast<uint4*>(wb + ((1 << 13) | (tid << 4))) = s1;
        *reinterpret_cast<uint4*>(wb + ((2 << 13) | (tid << 4))) = s2;
        *reinterpret_cast<uint4*>(wb + ((3 << 13) | (tid << 4))) = s3;
        // issue next chunk's global loads (consumed at next iteration's write)
        {
            int chn = (ch + 1 < CHUNKS) ? ch + 1 : ch;
            const unsigned char* src =
                (const unsigned char*)(memB + (cbase0 + (long)chn * BN) * D);
            s0 = *reinterpret_cast<const uint4*>(src + wsrcoff[0]);
            s1 = *reinterpret_cast<const uint4*>(src + wsrcoff[1]);
            s2 = *reinterpret_cast<const uint4*>(src + wsrcoff[2]);
            s3 = *reinterpret_cast<const uint4*>(src + wsrcoff[3]);
        }
        __syncthreads();   // single barrier per chunk (double-buffered LDS)

        const long cbase = cbase0 + (long)ch * BN;
        const float* mnp = memN + cbase + l15;
        float mn0 = mnp[0 * 16], mn1 = mnp[1 * 16], mn2 = mnp[2 * 16], mn3 = mnp[3 * 16];
        float mn4 = mnp[4 * 16], mn5 = mnp[5 * 16], mn6 = mnp[6 * 16], mn7 = mnp[7 * 16];

        const unsigned char* bp = &btile[ch & 1][0];
        DO_CG(0, mn0);
        DO_CG(1, mn1);
        DO_CG(2, mn2);
        DO_CG(3, mn3);
        DO_CG(4, mn4);
        DO_CG(5, mn5);
        DO_CG(6, mn6);
        DO_CG(7, mn7);
    }

    // exact merge across the 16 col-lanes of each row (4-level xor tree),
    // then lane l15==0 stores the per-(row,split) top-10
#define MERGE_STORE(T, LI) do { \
    mergeX(T, 1); mergeX(T, 2); mergeX(T, 4); mergeX(T, 8); \
    if (l15 == 0) { \
        int row = rbase + w * 32 + ((LI) >> 2) * 16 + lg * 4 + ((LI) & 3); \
        storeL(T, partials + (size_t)row * (NSPLIT * 10) + split * 10); \
    } \
} while (0)

    MERGE_STORE(T0, 0);
    MERGE_STORE(T1, 1);
    MERGE_STORE(T2, 2);
    MERGE_STORE(T3, 3);
    MERGE_STORE(T4, 4);
    MERGE_STORE(T5, 5);
    MERGE_STORE(T6, 6);
    MERGE_STORE(T7, 7);
}

// ---------------- kernel 4: final merge + mean of sqrt (1 wave / row) ----------------
__global__ __launch_bounds__(256)
void k_final(const float* __restrict__ partials, const float* __restrict__ encN,
             float* __restrict__ out)
{
    const int w = threadIdx.x >> 6;
    const int l = threadIdx.x & 63;
    const int row = blockIdx.x * 4 + w;

    L10 L;
    linit(L);
    const float* p = partials + (size_t)row * (NSPLIT * 10) + l * 5;
    ins(L, p[0]); ins(L, p[1]); ins(L, p[2]); ins(L, p[3]); ins(L, p[4]);
    mergeX(L, 1); mergeX(L, 2); mergeX(L, 4);
    mergeX(L, 8); mergeX(L, 16); mergeX(L, 32);
    if (l == 0) {
        float en = encN[row];
        float s = 0.f;
        s += sqrtf(fmaxf(en + L.a, 1e-12f));
        s += sqrtf(fmaxf(en + L.b, 1e-12f));
        s += sqrtf(fmaxf(en + L.c, 1e-12f));
        s += sqrtf(fmaxf(en + L.d, 1e-12f));
        s += sqrtf(fmaxf(en + L.e, 1e-12f));
        s += sqrtf(fmaxf(en + L.f, 1e-12f));
        s += sqrtf(fmaxf(en + L.g, 1e-12f));
        s += sqrtf(fmaxf(en + L.h, 1e-12f));
        s += sqrtf(fmaxf(en + L.i, 1e-12f));
        s += sqrtf(fmaxf(en + L.j, 1e-12f));
        out[row] = s * 0.1f;
    }
}

extern "C" void kernel_launch(void* const* d_in, const int* in_sizes, int n_in,
                              void* d_out, int out_size, void* d_ws, size_t ws_size,
                              hipStream_t stream)
{
    const float* state = (const float*)d_in[0];
    const float* W1    = (const float*)d_in[1];
    const float* b1    = (const float*)d_in[2];
    const float* W2    = (const float*)d_in[3];
    const float* b2    = (const float*)d_in[4];
    const float* mem   = (const float*)d_in[5];
    float* out = (float*)d_out;
    char* ws = (char*)d_ws;
    u16*   memB = (u16*)(ws + OFF_MEMB);
    float* memN = (float*)(ws + OFF_MEMN);
    u16*   encB = (u16*)(ws + OFF_ENCB);
    float* encN = (float*)(ws + OFF_ENCN);
    float* partials = (float*)(ws + OFF_PART);

    hipLaunchKernelGGL(k_encoder, dim3(NB / 8), dim3(128), 0, stream,
                       state, W1, b1, W2, b2, encB, encN);
    hipLaunchKernelGGL(k_memprep, dim3(CPAD * 32 / 256), dim3(256), 0, stream,
                       mem, memB, memN);
    hipLaunchKernelGGL(k_dist, dim3(NSPLIT, NB / BM), dim3(512), 0, stream,
                       encB, memB, memN, partials);
    hipLaunchKernelGGL(k_final, dim3(NB / 4), dim3(256), 0, stream,
                       partials, encN, out);
}